// Round 10
// baseline (101.084 us; speedup 1.0000x reference)
//
#include <hip/hip_runtime.h>

#define EPS_F 1e-8f
#define BLOCK 256
#define MAXGRID 2048   // 8 blocks/CU persistent -> 8 waves/SIMD

typedef float vf4 __attribute__((ext_vector_type(4)));

__device__ __forceinline__ vf4 load4u(const float* p) {
    vf4 v;
    __builtin_memcpy(&v, p, 16);   // align-4 16B load -> global_load_dwordx4
    return v;
}

__device__ __forceinline__ float fast_rcp(float x) {
    return __builtin_amdgcn_rcpf(x);  // v_rcp_f32, ~1 ulp
}

// Edge (a->b) contribution to 2*signed-Area(P ∩ [-W,W]x[-H,H]) via the
// boundary integral of h(y)=clamp(y,-H,H)+H over the edge clipped to the
// x-slab (vertical closure segments have dx=0 -> 0). Split at y=±H
// crossings; trapezoid per piece exact. Branch-free, NaN-free.
__device__ __forceinline__ float edge_contrib(float ax, float ay,
                                              float bx, float by,
                                              float W, float H) {
    float dx = bx - ax, dy = by - ay;
    float sdx = (fabsf(dx) < 1e-20f) ? 1e-20f : dx;
    float sdy = (fabsf(dy) < 1e-20f) ? 1e-20f : dy;
    float rdx = fast_rcp(sdx);
    float rdy = fast_rcp(sdy);

    float tA = (-W - ax) * rdx;
    float tB = ( W - ax) * rdx;
    float ta = fmaxf(fminf(tA, tB), 0.f);
    float tb = fminf(fmaxf(tA, tB), 1.f);
    tb = fmaxf(ta, tb);

    float u0 = (-H - ay) * rdy;
    float u1 = ( H - ay) * rdy;
    float tm0 = fminf(u0, u1), tm1 = fmaxf(u0, u1);
    float t1 = fminf(fmaxf(tm0, ta), tb);
    float t2 = fminf(fmaxf(tm1, ta), tb);

    float x0 = fmaf(ta, dx, ax), y0 = fmaf(ta, dy, ay);
    float x1 = fmaf(t1, dx, ax), y1 = fmaf(t1, dy, ay);
    float x2 = fmaf(t2, dx, ax), y2 = fmaf(t2, dy, ay);
    float x3 = fmaf(tb, dx, ax), y3 = fmaf(tb, dy, ay);
    float h0 = fminf(fmaxf(y0, -H), H) + H;
    float h1 = fminf(fmaxf(y1, -H), H) + H;
    float h2 = fminf(fmaxf(y2, -H), H) + H;
    float h3 = fminf(fmaxf(y3, -H), H) + H;

    return (x1 - x0) * (h0 + h1) + (x2 - x1) * (h1 + h2) + (x3 - x2) * (h2 + h3);
}

// Stage 1: persistent grid, depth-1 prefetch pipeline, per-block partial sum
// written to a DISTINCT slot in d_ws (no same-address atomic contention).
__global__ __launch_bounds__(BLOCK, 8) void iou3d_partial_kernel(
    const float* __restrict__ pred, const float* __restrict__ target,
    const float* __restrict__ weight, float* __restrict__ partials,
    int N, int stride, int iters)
{
    int i = blockIdx.x * BLOCK + threadIdx.x;

    // ---- prologue: prefetch element 0 ----
    int j = (i < N) ? i : 0;
    long o = (long)j * 7;
    vf4 A0 = load4u(pred + o),  A1 = load4u(pred + o + 3);
    vf4 B0 = load4u(target + o), B1 = load4u(target + o + 3);
    float wg = (i < N) ? weight[j] : 0.f;

    float val = 0.f;
    #pragma unroll 1
    for (int it = 0; it < iters; ++it) {
        // rotate pipeline: current <- prefetched
        vf4 a0 = A0, a1 = A1, b0 = B0, b1 = B1;
        float w = wg;

        // issue next element's loads (independent of compute below)
        int inext = i + stride;
        if (it + 1 < iters) {                 // wave-uniform branch
            int jn = (inext < N) ? inext : 0;
            long on = (long)jn * 7;
            A0 = load4u(pred + on);  A1 = load4u(pred + on + 3);
            B0 = load4u(target + on); B1 = load4u(target + on + 3);
            wg = (inext < N) ? weight[jn] : 0.f;
        }
        i = inext;

        // compute current element (hides the in-flight loads)
        // box: x=.x y=.y z=.z | w=.x h=.y l=.z yaw=.w
        float s1, c1, s2, c2;
        __sincosf(a1.w, &s1, &c1);
        __sincosf(b1.w, &s2, &c2);
        float cd = c1 * c2 + s1 * s2;          // cos(a2-a1)
        float sd = c1 * s2 - s1 * c2;          // sin(a2-a1)
        float dxc = b0.x - a0.x, dyc = b0.y - a0.y;
        float tx =  c1 * dxc + s1 * dyc;
        float ty = -s1 * dxc + c1 * dyc;
        float W = 0.5f * a1.x, H = 0.5f * a1.y;
        float w2 = 0.5f * b1.x, h2 = 0.5f * b1.y;

        float cw = cd * w2, sw = sd * w2, ch = cd * h2, sh = sd * h2;
        float q0x =  cw - sh + tx, q0y =  sw + ch + ty;
        float q1x = -cw - sh + tx, q1y = -sw + ch + ty;
        float q2x = -cw + sh + tx, q2y = -sw - ch + ty;
        float q3x =  cw + sh + tx, q3y =  sw - ch + ty;

        float s  = edge_contrib(q0x, q0y, q1x, q1y, W, H)
                 + edge_contrib(q1x, q1y, q2x, q2y, W, H)
                 + edge_contrib(q2x, q2y, q3x, q3y, W, H)
                 + edge_contrib(q3x, q3y, q0x, q0y, W, H);
        float area = 0.5f * fabsf(s);

        float zmax = fminf(a0.z + 0.5f * a1.z, b0.z + 0.5f * b1.z);
        float zmin = fmaxf(a0.z - 0.5f * a1.z, b0.z - 0.5f * b1.z);
        float inter3d = area * fmaxf(zmax - zmin, 0.f);
        float v1 = a1.x * a1.y * a1.z;
        float v2 = b1.x * b1.y * b1.z;
        float iou = inter3d * fast_rcp(v1 + v2 - inter3d + EPS_F);
        val += (1.f - iou) * w;
    }

    // ---- per-block reduction -> one plain store per block ----
    #pragma unroll
    for (int off = 32; off > 0; off >>= 1) val += __shfl_down(val, off, 64);
    __shared__ float wsum[4];
    int lane = threadIdx.x & 63, wid = threadIdx.x >> 6;
    if (lane == 0) wsum[wid] = val;
    __syncthreads();
    if (threadIdx.x == 0)
        partials[blockIdx.x] = wsum[0] + wsum[1] + wsum[2] + wsum[3];
}

// Stage 2: one block folds the partials and writes the mean (overwrites the
// poisoned d_out -> no zero kernel, no atomics anywhere).
__global__ __launch_bounds__(BLOCK) void reduce_partials_kernel(
    const float* __restrict__ partials, float* __restrict__ out,
    int nparts, float invN)
{
    float v = 0.f;
    for (int k = threadIdx.x; k < nparts; k += BLOCK) v += partials[k];
    #pragma unroll
    for (int off = 32; off > 0; off >>= 1) v += __shfl_down(v, off, 64);
    __shared__ float wsum[4];
    int lane = threadIdx.x & 63, wid = threadIdx.x >> 6;
    if (lane == 0) wsum[wid] = v;
    __syncthreads();
    if (threadIdx.x == 0)
        out[0] = (wsum[0] + wsum[1] + wsum[2] + wsum[3]) * invN;
}

extern "C" void kernel_launch(void* const* d_in, const int* in_sizes, int n_in,
                              void* d_out, int out_size, void* d_ws, size_t ws_size,
                              hipStream_t stream) {
    const float* pred   = (const float*)d_in[0];
    const float* target = (const float*)d_in[1];
    const float* weight = (const float*)d_in[2];
    float* out = (float*)d_out;
    float* partials = (float*)d_ws;
    int N = in_sizes[2];  // weight element count

    int nblocks = (N + BLOCK - 1) / BLOCK;
    int grid = (nblocks < MAXGRID) ? nblocks : MAXGRID;  // 8 blocks/CU persistent
    int stride = grid * BLOCK;
    int iters = (N + stride - 1) / stride;               // 2 for N = 1M

    iou3d_partial_kernel<<<grid, BLOCK, 0, stream>>>(pred, target, weight,
                                                     partials, N, stride, iters);
    reduce_partials_kernel<<<1, BLOCK, 0, stream>>>(partials, out, grid,
                                                    1.f / (float)N);
}

// Round 11
// 99.776 us; speedup vs baseline: 1.0131x; 1.0131x over previous
//
#include <hip/hip_runtime.h>

#define EPS_F 1e-8f
#define BLOCK 256
#define MAXGRID 2048   // 8 blocks/CU persistent -> 8 waves/SIMD

typedef float vf4 __attribute__((ext_vector_type(4)));

__device__ __forceinline__ vf4 load4u(const float* p) {
    vf4 v;
    __builtin_memcpy(&v, p, 16);
    return v;
}

__device__ __forceinline__ float fast_rcp(float x) {
    return __builtin_amdgcn_rcpf(x);  // v_rcp_f32, ~1 ulp
}

// Hardware sincos: v_sin_f32/v_cos_f32 take input in REVOLUTIONS with
// period 1; fract-reduce first (handles negatives: fract(-0.2)=0.8).
// Valid here since |yaw| < ~4.5 rad -- no Payne-Hanek needed (~5 instr
// vs ~300 for the inlined OCML __sincosf path).
__device__ __forceinline__ void fast_sincos(float x, float* s, float* c) {
    float t = x * 0.15915494309189535f;        // 1/(2*pi)
    t = __builtin_amdgcn_fractf(t);
    *s = __builtin_amdgcn_sinf(t);             // v_sin_f32: sin(2*pi*t)
    *c = __builtin_amdgcn_cosf(t);             // v_cos_f32: cos(2*pi*t)
}

// Edge (a->b) contribution to 2*signed-Area(P ∩ [-W,W]x[-H,H]) via the
// boundary integral of h(y)=clamp(y,-H,H)+H over the edge clipped to the
// x-slab (vertical closure segments have dx=0 -> 0). Split at y=±H
// crossings; trapezoid per piece exact. Branch-free, NaN-free.
__device__ __forceinline__ float edge_contrib(float ax, float ay,
                                              float bx, float by,
                                              float W, float H) {
    float dx = bx - ax, dy = by - ay;
    float sdx = (fabsf(dx) < 1e-20f) ? 1e-20f : dx;
    float sdy = (fabsf(dy) < 1e-20f) ? 1e-20f : dy;
    float rdx = fast_rcp(sdx);
    float rdy = fast_rcp(sdy);

    float tA = (-W - ax) * rdx;
    float tB = ( W - ax) * rdx;
    float ta = fmaxf(fminf(tA, tB), 0.f);
    float tb = fminf(fmaxf(tA, tB), 1.f);
    tb = fmaxf(ta, tb);

    float u0 = (-H - ay) * rdy;
    float u1 = ( H - ay) * rdy;
    float tm0 = fminf(u0, u1), tm1 = fmaxf(u0, u1);
    float t1 = fminf(fmaxf(tm0, ta), tb);      // v_med3 patterns
    float t2 = fminf(fmaxf(tm1, ta), tb);

    float x0 = fmaf(ta, dx, ax), y0 = fmaf(ta, dy, ay);
    float x1 = fmaf(t1, dx, ax), y1 = fmaf(t1, dy, ay);
    float x2 = fmaf(t2, dx, ax), y2 = fmaf(t2, dy, ay);
    float x3 = fmaf(tb, dx, ax), y3 = fmaf(tb, dy, ay);
    float h0 = fminf(fmaxf(y0, -H), H) + H;
    float h1 = fminf(fmaxf(y1, -H), H) + H;
    float h2 = fminf(fmaxf(y2, -H), H) + H;
    float h3 = fminf(fmaxf(y3, -H), H) + H;

    return (x1 - x0) * (h0 + h1) + (x2 - x1) * (h1 + h2) + (x3 - x2) * (h2 + h3);
}

// Stage 1: persistent grid, depth-1 prefetch pipeline, per-block partial
// to a distinct d_ws slot (no same-address atomics).
__global__ __launch_bounds__(BLOCK, 8) void iou3d_partial_kernel(
    const float* __restrict__ pred, const float* __restrict__ target,
    const float* __restrict__ weight, float* __restrict__ partials,
    int N, int stride, int iters)
{
    int i = blockIdx.x * BLOCK + threadIdx.x;

    int j = (i < N) ? i : 0;
    long o = (long)j * 7;
    vf4 A0 = load4u(pred + o),  A1 = load4u(pred + o + 3);
    vf4 B0 = load4u(target + o), B1 = load4u(target + o + 3);
    float wg = (i < N) ? weight[j] : 0.f;

    float val = 0.f;
    #pragma unroll 1
    for (int it = 0; it < iters; ++it) {
        vf4 a0 = A0, a1 = A1, b0 = B0, b1 = B1;
        float w = wg;

        int inext = i + stride;
        if (it + 1 < iters) {                 // wave-uniform branch
            int jn = (inext < N) ? inext : 0;
            long on = (long)jn * 7;
            A0 = load4u(pred + on);  A1 = load4u(pred + on + 3);
            B0 = load4u(target + on); B1 = load4u(target + on + 3);
            wg = (inext < N) ? weight[jn] : 0.f;
        }
        i = inext;

        // box: x=.x y=.y z=.z | w=.x h=.y l=.z yaw=.w
        float s1, c1, sd, cd;
        fast_sincos(a1.w, &s1, &c1);           // frame rotation
        fast_sincos(b1.w - a1.w, &sd, &cd);    // relative rotation directly
        float dxc = b0.x - a0.x, dyc = b0.y - a0.y;
        float tx =  c1 * dxc + s1 * dyc;
        float ty = -s1 * dxc + c1 * dyc;
        float W = 0.5f * a1.x, H = 0.5f * a1.y;
        float w2 = 0.5f * b1.x, h2 = 0.5f * b1.y;

        float cw = cd * w2, sw = sd * w2, ch = cd * h2, sh = sd * h2;
        float q0x =  cw - sh + tx, q0y =  sw + ch + ty;
        float q1x = -cw - sh + tx, q1y = -sw + ch + ty;
        float q2x = -cw + sh + tx, q2y = -sw - ch + ty;
        float q3x =  cw + sh + tx, q3y =  sw - ch + ty;

        float s  = edge_contrib(q0x, q0y, q1x, q1y, W, H)
                 + edge_contrib(q1x, q1y, q2x, q2y, W, H)
                 + edge_contrib(q2x, q2y, q3x, q3y, W, H)
                 + edge_contrib(q3x, q3y, q0x, q0y, W, H);
        float area = 0.5f * fabsf(s);

        float zmax = fminf(a0.z + 0.5f * a1.z, b0.z + 0.5f * b1.z);
        float zmin = fmaxf(a0.z - 0.5f * a1.z, b0.z - 0.5f * b1.z);
        float inter3d = area * fmaxf(zmax - zmin, 0.f);
        float v1 = a1.x * a1.y * a1.z;
        float v2 = b1.x * b1.y * b1.z;
        float iou = inter3d * fast_rcp(v1 + v2 - inter3d + EPS_F);
        val += (1.f - iou) * w;
    }

    #pragma unroll
    for (int off = 32; off > 0; off >>= 1) val += __shfl_down(val, off, 64);
    __shared__ float wsum[4];
    int lane = threadIdx.x & 63, wid = threadIdx.x >> 6;
    if (lane == 0) wsum[wid] = val;
    __syncthreads();
    if (threadIdx.x == 0)
        partials[blockIdx.x] = wsum[0] + wsum[1] + wsum[2] + wsum[3];
}

// Stage 2: fold partials, write mean (overwrites poisoned d_out).
__global__ __launch_bounds__(BLOCK) void reduce_partials_kernel(
    const float* __restrict__ partials, float* __restrict__ out,
    int nparts, float invN)
{
    float v = 0.f;
    for (int k = threadIdx.x; k < nparts; k += BLOCK) v += partials[k];
    #pragma unroll
    for (int off = 32; off > 0; off >>= 1) v += __shfl_down(v, off, 64);
    __shared__ float wsum[4];
    int lane = threadIdx.x & 63, wid = threadIdx.x >> 6;
    if (lane == 0) wsum[wid] = v;
    __syncthreads();
    if (threadIdx.x == 0)
        out[0] = (wsum[0] + wsum[1] + wsum[2] + wsum[3]) * invN;
}

extern "C" void kernel_launch(void* const* d_in, const int* in_sizes, int n_in,
                              void* d_out, int out_size, void* d_ws, size_t ws_size,
                              hipStream_t stream) {
    const float* pred   = (const float*)d_in[0];
    const float* target = (const float*)d_in[1];
    const float* weight = (const float*)d_in[2];
    float* out = (float*)d_out;
    float* partials = (float*)d_ws;
    int N = in_sizes[2];  // weight element count

    int nblocks = (N + BLOCK - 1) / BLOCK;
    int grid = (nblocks < MAXGRID) ? nblocks : MAXGRID;
    int stride = grid * BLOCK;
    int iters = (N + stride - 1) / stride;    // 2 for N = 1M

    iou3d_partial_kernel<<<grid, BLOCK, 0, stream>>>(pred, target, weight,
                                                     partials, N, stride, iters);
    reduce_partials_kernel<<<1, BLOCK, 0, stream>>>(partials, out, grid,
                                                    1.f / (float)N);
}

// Round 12
// 98.417 us; speedup vs baseline: 1.0271x; 1.0138x over previous
//
#include <hip/hip_runtime.h>

#define EPS_F 1e-8f
#define BLOCK 256
#define GRID  1024        // 4 blocks/CU, persistent
#define SLAB_CH 896       // dwordx4 chunks per slab (256 elem × 14 dwords / 4)

typedef float vf4 __attribute__((ext_vector_type(4)));

__device__ __forceinline__ vf4 load4u(const float* p) {
    vf4 v;
    __builtin_memcpy(&v, p, 16);
    return v;
}

__device__ __forceinline__ float fast_rcp(float x) {
    return __builtin_amdgcn_rcpf(x);
}

// HW sincos in revolutions; |yaw| < ~4.5 rad so fract-reduction suffices.
__device__ __forceinline__ void fast_sincos(float x, float* s, float* c) {
    float t = x * 0.15915494309189535f;
    t = __builtin_amdgcn_fractf(t);
    *s = __builtin_amdgcn_sinf(t);
    *c = __builtin_amdgcn_cosf(t);
}

// Edge contribution to 2*signed-Area(P ∩ [-W,W]x[-H,H]); boundary integral
// of h(y)=clamp(y,-H,H)+H over the edge clipped to the x-slab. rdx/rdy are
// (guarded) reciprocals of dx/dy, shareable between parallel edges (sign
// flips cancel in the min/max clamps).
__device__ __forceinline__ float edge_contrib(float ax, float ay,
                                              float dx, float dy,
                                              float rdx, float rdy,
                                              float W, float H) {
    float tA = (-W - ax) * rdx;
    float tB = ( W - ax) * rdx;
    float ta = fmaxf(fminf(tA, tB), 0.f);
    float tb = fminf(fmaxf(tA, tB), 1.f);
    tb = fmaxf(ta, tb);

    float u0 = (-H - ay) * rdy;
    float u1 = ( H - ay) * rdy;
    float tm0 = fminf(u0, u1), tm1 = fmaxf(u0, u1);
    float t1 = fminf(fmaxf(tm0, ta), tb);
    float t2 = fminf(fmaxf(tm1, ta), tb);

    float x0 = fmaf(ta, dx, ax), y0 = fmaf(ta, dy, ay);
    float x1 = fmaf(t1, dx, ax), y1 = fmaf(t1, dy, ay);
    float x2 = fmaf(t2, dx, ax), y2 = fmaf(t2, dy, ay);
    float x3 = fmaf(tb, dx, ax), y3 = fmaf(tb, dy, ay);
    float h0 = fminf(fmaxf(y0, -H), H) + H;
    float h1 = fminf(fmaxf(y1, -H), H) + H;
    float h2 = fminf(fmaxf(y2, -H), H) + H;
    float h3 = fminf(fmaxf(y3, -H), H) + H;

    return (x1 - x0) * (h0 + h1) + (x2 - x1) * (h1 + h2) + (x3 - x2) * (h2 + h3);
}

// Persistent, double-buffered LDS pipeline:
//   stage slab0 -> barrier -> [issue dense loads slab k+1 | compute slab k
//   from LDS | ds_write slab k+1 | barrier] x iters
// Global loads are stride-1 dwordx4 (fully coalesced); the vmcnt drain sits
// AFTER the compute, so load latency is hidden by real work, not a barrier.
__global__ __launch_bounds__(BLOCK, 4) void iou3d_partial_kernel(
    const float* __restrict__ pred, const float* __restrict__ target,
    const float* __restrict__ weight, float* __restrict__ partials,
    int N, int stride_e, int iters)
{
    __shared__ vf4 lds4[2 * SLAB_CH];            // 28 KB
    const int tid = threadIdx.x;
    const long maxdw = 7L * N - 4;

    // chunk descriptors for this thread (k=0..3; c<896 -> waves 2,3 idle at k=3)
    // lds dword = 4c for both halves (target base 1792 = 4*448)
    // global: c<448 -> pred[g0+4c]; c>=448 -> target[g0+4c-1792]

    // ---- prologue: stage slab 0 ----
    {
        long g0 = (long)blockIdx.x * 256 * 7;
        #pragma unroll
        for (int k = 0; k < 4; ++k) {
            int c = k * BLOCK + tid;
            if (c < SLAB_CH) {
                bool isP = (c < 448);
                long gdw = g0 + 4L * c - (isP ? 0 : 1792);
                gdw = (gdw > maxdw) ? maxdw : gdw;
                lds4[c] = load4u((isP ? pred : target) + gdw);
            }
        }
    }
    int i0 = blockIdx.x * 256 + tid;
    float wcur = (i0 < N) ? weight[i0] : 0.f;
    __syncthreads();

    float val = 0.f;
    #pragma unroll 1
    for (int it = 0; it < iters; ++it) {
        bool more = (it + 1 < iters);

        // ---- issue next slab's dense loads (no wait) ----
        vf4 R0, R1, R2, R3;
        float wnext = 0.f;
        if (more) {
            long g0 = ((long)blockIdx.x * 256 + (long)(it + 1) * stride_e) * 7;
            {
                int c = tid;              long g = g0 + 4L * c;
                g = (g > maxdw) ? maxdw : g;  R0 = load4u(pred + g);
            }
            {
                int c = BLOCK + tid;      long g = g0 + 4L * c;
                g = (g > maxdw) ? maxdw : g;  R1 = load4u(pred + g);  // c<448? c in [256,512): crosses into target half
            }
            {
                int c = 2 * BLOCK + tid;  long g = g0 + 4L * c - 1792;
                g = (g > maxdw) ? maxdw : g;  R2 = load4u(target + g);
            }
            {
                int c = 3 * BLOCK + tid;  // valid only for tid<128
                long g = g0 + 4L * c - 1792;
                g = (g < 0) ? 0 : ((g > maxdw) ? maxdw : g);
                R3 = load4u(target + g);
            }
            int inext = blockIdx.x * 256 + (it + 1) * stride_e + tid;
            wnext = (inext < N) ? weight[inext] : 0.f;
        }

        // fix R1's source: chunks [256,448) are pred, [448,512) are target
        // (handled below at ds_write by re-issuing for the target part is
        //  wasteful; instead split correctly here)
        // NOTE: R1 loaded from pred unconditionally above is WRONG for
        // c>=448; correct it: reload those lanes from target.
        if (more) {
            int c = BLOCK + tid;
            if (c >= 448) {
                long g0 = ((long)blockIdx.x * 256 + (long)(it + 1) * stride_e) * 7;
                long g = g0 + 4L * c - 1792;
                g = (g > maxdw) ? maxdw : g;
                R1 = load4u(target + g);
            }
        }

        // ---- compute current slab from LDS ----
        {
            const float* ldsf = (const float*)(lds4 + (it & 1) * 0); // single view
            // double buffer: buffer select by parity
            const float* base = (const float*)lds4;
            const float* p;
            const float* q;
            // buffers laid out [buf0 | buf1], each SLAB_CH vf4
            // (it&1) selects buffer
            p = base + (size_t)(it & 1) * (SLAB_CH * 4) + 7 * tid;
            q = p + 1792;
            (void)ldsf;

            float a0 = p[0], a1 = p[1], a2 = p[2], a3 = p[3], a4 = p[4], a5 = p[5], a6 = p[6];
            float b0 = q[0], b1 = q[1], b2 = q[2], b3 = q[3], b4 = q[4], b5 = q[5], b6 = q[6];

            float s1, c1, sd, cd;
            fast_sincos(a6, &s1, &c1);
            fast_sincos(b6 - a6, &sd, &cd);
            float dxc = b0 - a0, dyc = b1 - a1;
            float tx =  c1 * dxc + s1 * dyc;
            float ty = -s1 * dxc + c1 * dyc;
            float W = 0.5f * a3, H = 0.5f * a4;
            float w2 = 0.5f * b3, h2 = 0.5f * b4;

            float cw = cd * w2, sw = sd * w2, ch = cd * h2, sh = sd * h2;
            float q0x =  cw - sh + tx, q0y =  sw + ch + ty;
            float q1x = -cw - sh + tx, q1y = -sw + ch + ty;
            float q2x = -cw + sh + tx, q2y = -sw - ch + ty;
            float q3x =  cw + sh + tx, q3y =  sw - ch + ty;

            // parallel-edge rcp sharing: e0=q1-q0=(-2cw,-2sw), e1=q2-q1=(2sh,-2ch)
            float e0x = -2.f * cw, e0y = -2.f * sw;
            float e1x =  2.f * sh, e1y = -2.f * ch;
            float g0x = (fabsf(e0x) < 1e-20f) ? 1e-20f : e0x;
            float g0y = (fabsf(e0y) < 1e-20f) ? 1e-20f : e0y;
            float g1x = (fabsf(e1x) < 1e-20f) ? 1e-20f : e1x;
            float g1y = (fabsf(e1y) < 1e-20f) ? 1e-20f : e1y;
            float r0x = fast_rcp(g0x), r0y = fast_rcp(g0y);
            float r1x = fast_rcp(g1x), r1y = fast_rcp(g1y);

            float s = edge_contrib(q0x, q0y,  e0x,  e0y,  r0x,  r0y, W, H)
                    + edge_contrib(q1x, q1y,  e1x,  e1y,  r1x,  r1y, W, H)
                    + edge_contrib(q2x, q2y, -e0x, -e0y, -r0x, -r0y, W, H)
                    + edge_contrib(q3x, q3y, -e1x, -e1y, -r1x, -r1y, W, H);
            float area = 0.5f * fabsf(s);

            float zmax = fminf(a2 + 0.5f * a5, b2 + 0.5f * b5);
            float zmin = fmaxf(a2 - 0.5f * a5, b2 - 0.5f * b5);
            float inter3d = area * fmaxf(zmax - zmin, 0.f);
            float v1 = a3 * a4 * a5;
            float v2 = b3 * b4 * b5;
            float iou = inter3d * fast_rcp(v1 + v2 - inter3d + EPS_F);
            val += (1.f - iou) * wcur;
        }

        // ---- write next slab into the other buffer (vmcnt drain lands here) ----
        if (more) {
            vf4* dst = lds4 + ((it + 1) & 1) * SLAB_CH;
            dst[tid]             = R0;
            dst[BLOCK + tid]     = R1;
            dst[2 * BLOCK + tid] = R2;
            if (3 * BLOCK + tid < SLAB_CH) dst[3 * BLOCK + tid] = R3;
        }
        __syncthreads();
        wcur = wnext;
    }

    // ---- block reduction -> distinct partial slot ----
    #pragma unroll
    for (int off = 32; off > 0; off >>= 1) val += __shfl_down(val, off, 64);
    __shared__ float wsum[4];
    int lane = tid & 63, wid = tid >> 6;
    if (lane == 0) wsum[wid] = val;
    __syncthreads();
    if (tid == 0)
        partials[blockIdx.x] = wsum[0] + wsum[1] + wsum[2] + wsum[3];
}

__global__ __launch_bounds__(BLOCK) void reduce_partials_kernel(
    const float* __restrict__ partials, float* __restrict__ out,
    int nparts, float invN)
{
    float v = 0.f;
    for (int k = threadIdx.x; k < nparts; k += BLOCK) v += partials[k];
    #pragma unroll
    for (int off = 32; off > 0; off >>= 1) v += __shfl_down(v, off, 64);
    __shared__ float wsum[4];
    int lane = threadIdx.x & 63, wid = threadIdx.x >> 6;
    if (lane == 0) wsum[wid] = v;
    __syncthreads();
    if (threadIdx.x == 0)
        out[0] = (wsum[0] + wsum[1] + wsum[2] + wsum[3]) * invN;
}

extern "C" void kernel_launch(void* const* d_in, const int* in_sizes, int n_in,
                              void* d_out, int out_size, void* d_ws, size_t ws_size,
                              hipStream_t stream) {
    const float* pred   = (const float*)d_in[0];
    const float* target = (const float*)d_in[1];
    const float* weight = (const float*)d_in[2];
    float* out = (float*)d_out;
    float* partials = (float*)d_ws;
    int N = in_sizes[2];

    int nblocks = (N + BLOCK - 1) / BLOCK;
    int grid = (nblocks < GRID) ? nblocks : GRID;
    int stride_e = grid * BLOCK;                 // elements per iteration round
    int iters = (N + stride_e - 1) / stride_e;   // 4 for N = 1M

    iou3d_partial_kernel<<<grid, BLOCK, 0, stream>>>(pred, target, weight,
                                                     partials, N, stride_e, iters);
    reduce_partials_kernel<<<1, BLOCK, 0, stream>>>(partials, out, grid,
                                                    1.f / (float)N);
}

// Round 13
// 95.235 us; speedup vs baseline: 1.0614x; 1.0334x over previous
//
#include <hip/hip_runtime.h>

#define EPS_F 1e-8f
#define BLOCK 256
#define GRID  1024                  // 4 blocks/CU, persistent
#define SLAB_CH 896                 // 16B chunks per slab (256 elem × 14 dw / 4)
#define SLAB_DW (SLAB_CH * 4)       // 3584 dwords per slab

typedef float vf4 __attribute__((ext_vector_type(4)));

typedef const __attribute__((address_space(1))) void* gptr_t;
typedef __attribute__((address_space(3))) void* sptr_t;

__device__ __forceinline__ vf4 load4u(const float* p) {
    vf4 v; __builtin_memcpy(&v, p, 16); return v;
}
__device__ __forceinline__ float fast_rcp(float x) {
    return __builtin_amdgcn_rcpf(x);
}
// HW sincos in revolutions; |yaw| < ~4.5 rad so fract-reduction suffices.
__device__ __forceinline__ void fast_sincos(float x, float* s, float* c) {
    float t = x * 0.15915494309189535f;
    t = __builtin_amdgcn_fractf(t);
    *s = __builtin_amdgcn_sinf(t);
    *c = __builtin_amdgcn_cosf(t);
}

// Edge contribution to 2*signed-Area(P ∩ [-W,W]x[-H,H]); boundary integral
// of h(y)=clamp(y,-H,H)+H over the edge clipped to the x-slab. rdx/rdy
// shareable between parallel edges (sign flips cancel in min/max).
__device__ __forceinline__ float edge_contrib(float ax, float ay,
                                              float dx, float dy,
                                              float rdx, float rdy,
                                              float W, float H) {
    float tA = (-W - ax) * rdx;
    float tB = ( W - ax) * rdx;
    float ta = fmaxf(fminf(tA, tB), 0.f);
    float tb = fminf(fmaxf(tA, tB), 1.f);
    tb = fmaxf(ta, tb);

    float u0 = (-H - ay) * rdy;
    float u1 = ( H - ay) * rdy;
    float tm0 = fminf(u0, u1), tm1 = fmaxf(u0, u1);
    float t1 = fminf(fmaxf(tm0, ta), tb);
    float t2 = fminf(fmaxf(tm1, ta), tb);

    float x0 = fmaf(ta, dx, ax), y0 = fmaf(ta, dy, ay);
    float x1 = fmaf(t1, dx, ax), y1 = fmaf(t1, dy, ay);
    float x2 = fmaf(t2, dx, ax), y2 = fmaf(t2, dy, ay);
    float x3 = fmaf(tb, dx, ax), y3 = fmaf(tb, dy, ay);
    float h0 = fminf(fmaxf(y0, -H), H) + H;
    float h1 = fminf(fmaxf(y1, -H), H) + H;
    float h2 = fminf(fmaxf(y2, -H), H) + H;
    float h3 = fminf(fmaxf(y3, -H), H) + H;

    return (x1 - x0) * (h0 + h1) + (x2 - x1) * (h1 + h2) + (x3 - x2) * (h2 + h3);
}

// Shared per-element IoU-loss computation (reads one element from LDS view).
__device__ __forceinline__ float elem_loss(const float* p, const float* q,
                                           float wgt) {
    float a0=p[0],a1=p[1],a2=p[2],a3=p[3],a4=p[4],a5=p[5],a6=p[6];
    float b0=q[0],b1=q[1],b2=q[2],b3=q[3],b4=q[4],b5=q[5],b6=q[6];

    float s1, c1, sd, cd;
    fast_sincos(a6, &s1, &c1);
    fast_sincos(b6 - a6, &sd, &cd);
    float dxc = b0 - a0, dyc = b1 - a1;
    float tx =  c1 * dxc + s1 * dyc;
    float ty = -s1 * dxc + c1 * dyc;
    float W = 0.5f * a3, H = 0.5f * a4;
    float w2 = 0.5f * b3, h2 = 0.5f * b4;

    float cw = cd * w2, sw = sd * w2, ch = cd * h2, sh = sd * h2;
    float q0x =  cw - sh + tx, q0y =  sw + ch + ty;
    float q1x = -cw - sh + tx, q1y = -sw + ch + ty;
    float q2x = -cw + sh + tx, q2y = -sw - ch + ty;
    float q3x =  cw + sh + tx, q3y =  sw - ch + ty;

    float e0x = -2.f * cw, e0y = -2.f * sw;   // q1-q0
    float e1x =  2.f * sh, e1y = -2.f * ch;   // q2-q1
    float g0x = (fabsf(e0x) < 1e-20f) ? 1e-20f : e0x;
    float g0y = (fabsf(e0y) < 1e-20f) ? 1e-20f : e0y;
    float g1x = (fabsf(e1x) < 1e-20f) ? 1e-20f : e1x;
    float g1y = (fabsf(e1y) < 1e-20f) ? 1e-20f : e1y;
    float r0x = fast_rcp(g0x), r0y = fast_rcp(g0y);
    float r1x = fast_rcp(g1x), r1y = fast_rcp(g1y);

    float s = edge_contrib(q0x, q0y,  e0x,  e0y,  r0x,  r0y, W, H)
            + edge_contrib(q1x, q1y,  e1x,  e1y,  r1x,  r1y, W, H)
            + edge_contrib(q2x, q2y, -e0x, -e0y, -r0x, -r0y, W, H)
            + edge_contrib(q3x, q3y, -e1x, -e1y, -r1x, -r1y, W, H);
    float area = 0.5f * fabsf(s);

    float zmax = fminf(a2 + 0.5f * a5, b2 + 0.5f * b5);
    float zmin = fmaxf(a2 - 0.5f * a5, b2 - 0.5f * b5);
    float inter3d = area * fmaxf(zmax - zmin, 0.f);
    float v1 = a3 * a4 * a5;
    float v2 = b3 * b4 * b5;
    float iou = inter3d * fast_rcp(v1 + v2 - inter3d + EPS_F);
    return (1.f - iou) * wgt;
}

// Fast path (N divisible by GRID*BLOCK*iters): double-buffered LDS pipeline
// with async global->LDS DMA (global_load_lds width=16). No VGPR round-trip,
// no ds_write; __syncthreads drains the DMA after compute has hidden it.
// Chunk->wave mapping is wave-uniform base + lane*16 (pred/target split at
// c=448 lands exactly on the tid=192 wave boundary).
__global__ __launch_bounds__(BLOCK, 4) void iou3d_partial_dma(
    const float* __restrict__ pred, const float* __restrict__ target,
    const float* __restrict__ weight, float* __restrict__ partials,
    int stride_e, int iters)
{
    __shared__ vf4 lds4[2 * SLAB_CH];            // 28 KB
    const int tid = threadIdx.x;

    auto stage = [&](int it, int buf) {
        long g0 = ((long)blockIdx.x * BLOCK + (long)it * stride_e) * 7;
        #pragma unroll
        for (int k = 0; k < 3; ++k) {
            int c = k * BLOCK + tid;             // waves uniform per source
            const float* src = (c < 448) ? pred + g0 + 4L * c
                                         : target + g0 + 4L * c - SLAB_DW / 2;
            __builtin_amdgcn_global_load_lds((gptr_t)src,
                                             (sptr_t)&lds4[buf * SLAB_CH + c],
                                             16, 0, 0);
        }
        if (tid < 128) {                         // waves 0,1: c = 768..895
            int c = 3 * BLOCK + tid;
            const float* src = target + g0 + 4L * c - SLAB_DW / 2;
            __builtin_amdgcn_global_load_lds((gptr_t)src,
                                             (sptr_t)&lds4[buf * SLAB_CH + c],
                                             16, 0, 0);
        }
    };

    stage(0, 0);
    int i0 = blockIdx.x * BLOCK + tid;
    float wcur = weight[i0];
    __syncthreads();

    float val = 0.f;
    #pragma unroll 1
    for (int it = 0; it < iters; ++it) {
        bool more = (it + 1 < iters);
        if (more) stage(it + 1, (it + 1) & 1);   // fire-and-forget DMA
        float wnext = more ? weight[i0 + (it + 1) * stride_e] : 0.f;

        const float* base = (const float*)lds4 + (size_t)(it & 1) * SLAB_DW;
        val += elem_loss(base + 7 * tid, base + SLAB_DW / 2 + 7 * tid, wcur);

        wcur = wnext;
        __syncthreads();                         // drains DMA (vmcnt) + barrier
    }

    #pragma unroll
    for (int off = 32; off > 0; off >>= 1) val += __shfl_down(val, off, 64);
    __shared__ float wsum[4];
    int lane = tid & 63, wid = tid >> 6;
    if (lane == 0) wsum[wid] = val;
    __syncthreads();
    if (tid == 0)
        partials[blockIdx.x] = wsum[0] + wsum[1] + wsum[2] + wsum[3];
}

// Generic fallback (any N): register-prefetch pipeline (R9 structure).
__global__ __launch_bounds__(BLOCK, 4) void iou3d_partial_gen(
    const float* __restrict__ pred, const float* __restrict__ target,
    const float* __restrict__ weight, float* __restrict__ partials,
    int N, int stride_e, int iters)
{
    int i = blockIdx.x * BLOCK + threadIdx.x;
    int j = (i < N) ? i : 0;
    long o = (long)j * 7;
    vf4 A0 = load4u(pred + o),  A1 = load4u(pred + o + 3);
    vf4 B0 = load4u(target + o), B1 = load4u(target + o + 3);
    float wg = (i < N) ? weight[j] : 0.f;

    float val = 0.f;
    #pragma unroll 1
    for (int it = 0; it < iters; ++it) {
        vf4 a0 = A0, a1 = A1, b0 = B0, b1 = B1;
        float w = wg;
        int inext = i + stride_e;
        if (it + 1 < iters) {
            int jn = (inext < N) ? inext : 0;
            long on = (long)jn * 7;
            A0 = load4u(pred + on);  A1 = load4u(pred + on + 3);
            B0 = load4u(target + on); B1 = load4u(target + on + 3);
            wg = (inext < N) ? weight[jn] : 0.f;
        }
        i = inext;
        float rec[14] = {a0.x,a0.y,a0.z,a0.w,a1.y,a1.z,a1.w,
                         b0.x,b0.y,b0.z,b0.w,b1.y,b1.z,b1.w};
        val += elem_loss(rec, rec + 7, w);
    }

    #pragma unroll
    for (int off = 32; off > 0; off >>= 1) val += __shfl_down(val, off, 64);
    __shared__ float wsum[4];
    int lane = threadIdx.x & 63, wid = threadIdx.x >> 6;
    if (lane == 0) wsum[wid] = val;
    __syncthreads();
    if (threadIdx.x == 0)
        partials[blockIdx.x] = wsum[0] + wsum[1] + wsum[2] + wsum[3];
}

__global__ __launch_bounds__(BLOCK) void reduce_partials_kernel(
    const float* __restrict__ partials, float* __restrict__ out,
    int nparts, float invN)
{
    float v = 0.f;
    for (int k = threadIdx.x; k < nparts; k += BLOCK) v += partials[k];
    #pragma unroll
    for (int off = 32; off > 0; off >>= 1) v += __shfl_down(v, off, 64);
    __shared__ float wsum[4];
    int lane = threadIdx.x & 63, wid = threadIdx.x >> 6;
    if (lane == 0) wsum[wid] = v;
    __syncthreads();
    if (threadIdx.x == 0)
        out[0] = (wsum[0] + wsum[1] + wsum[2] + wsum[3]) * invN;
}

extern "C" void kernel_launch(void* const* d_in, const int* in_sizes, int n_in,
                              void* d_out, int out_size, void* d_ws, size_t ws_size,
                              hipStream_t stream) {
    const float* pred   = (const float*)d_in[0];
    const float* target = (const float*)d_in[1];
    const float* weight = (const float*)d_in[2];
    float* out = (float*)d_out;
    float* partials = (float*)d_ws;
    int N = in_sizes[2];

    int nblocks = (N + BLOCK - 1) / BLOCK;
    int grid = (nblocks < GRID) ? nblocks : GRID;
    int stride_e = grid * BLOCK;
    int iters = (N + stride_e - 1) / stride_e;

    if (N % stride_e == 0) {   // exact tiling (true for harness N = 2^20)
        iou3d_partial_dma<<<grid, BLOCK, 0, stream>>>(pred, target, weight,
                                                      partials, stride_e, iters);
    } else {
        iou3d_partial_gen<<<grid, BLOCK, 0, stream>>>(pred, target, weight,
                                                      partials, N, stride_e, iters);
    }
    reduce_partials_kernel<<<1, BLOCK, 0, stream>>>(partials, out, grid,
                                                    1.f / (float)N);
}